// Round 10
// baseline (366.526 us; speedup 1.0000x reference)
//
#include <hip/hip_runtime.h>
#include <hip/hip_bf16.h>

// ---------------------------------------------------------------------------
// HeteroGNN forward (round 10):
//   - GEMM: A loads are now COALESCED (lane-contiguous dwordx4, 2 full rows
//     per instruction) -> LDS f32 with 528B padded stride -> ds_read_b128
//     (2-way, free) -> cvt -> MFMA. Rounds 5-9 were A-pattern-bound at
//     ~1.6 TB/s (16-row scatter per vmem instr). BM=32/BN=128/BK=128,
//     48.6 KB LDS, 3 blocks/CU, grid 1250.
//   - fixed-capacity adjacency, gather-based aggregation, fused posts
// ---------------------------------------------------------------------------

#define H 128
#define K_DIM 1280
#define LIG_IN 4
#define CAP_L 24    // max ligand degree (lambda=2.5; observed max ~13)
#define CAP_T 48    // max target degree (lambda=12.5; observed max ~34)

typedef __attribute__((ext_vector_type(8))) short bf16x8;
typedef __attribute__((ext_vector_type(4))) float f32x4;

#define AS1(p) ((const __attribute__((address_space(1))) void*)(p))
#define AS3(p) ((__attribute__((address_space(3))) void*)(p))

// ---- kernel 1: build both fixed-capacity adjacencies ----------------------
__global__ void fill_both(const int* __restrict__ src, const int* __restrict__ dst,
                          int* __restrict__ cur_l, int* __restrict__ cur_t,
                          int* __restrict__ adjd, int* __restrict__ adjs, int E)
{
    int e = blockIdx.x * blockDim.x + threadIdx.x;
    if (e >= E) return;
    int s = src[e], d = dst[e];
    int p = atomicAdd(&cur_l[s], 1);
    adjd[s * CAP_L + p] = d;
    int q = atomicAdd(&cur_t[d], 1);
    adjs[d * CAP_T + q] = s;
}

// ---- cast weights: Wt[n][k]; n<128 -> W_tl_l (y_tl), n>=128 -> W_lt_r -----
__global__ void cast_wt(const float* __restrict__ Wl, const float* __restrict__ Wr,
                        __hip_bfloat16* __restrict__ Wt, int n)
{
    int idx = blockIdx.x * blockDim.x + threadIdx.x;
    if (idx >= n) return;
    int nr = idx / K_DIM, k = idx - nr * K_DIM;
    float v = (nr < H) ? Wl[k * H + nr] : Wr[k * H + (nr - H)];
    Wt[idx] = __float2bfloat16(v);
}

// ---- GEMM: [M,1280] f32 @ [1280,256] bf16 -> y_tl | t_lin (f32) -----------
__device__ inline bf16x8 cvt8(float4 u, float4 v)
{
    union { __hip_bfloat16 h[8]; bf16x8 f; } r;
    r.h[0] = __float2bfloat16(u.x); r.h[1] = __float2bfloat16(u.y);
    r.h[2] = __float2bfloat16(u.z); r.h[3] = __float2bfloat16(u.w);
    r.h[4] = __float2bfloat16(v.x); r.h[5] = __float2bfloat16(v.y);
    r.h[6] = __float2bfloat16(v.z); r.h[7] = __float2bfloat16(v.w);
    return r.f;
}

#define NCHUNK 10          // K_DIM / 128
#define AROW 132           // A LDS row stride in floats (528 B): 2-way banks
__global__ __launch_bounds__(256, 3)
void gemm_fused(const float* __restrict__ Xf,          // [M,1280] f32
                const unsigned short* __restrict__ Wt, // [256,1280] bf16 n-major
                float* __restrict__ y_tl, float* __restrict__ t_lin, int M)
{
    __shared__ float As[32 * AROW];   // 16.9 KB, chunk of A as f32
    __shared__ short Bs[128 * 128];   // 32 KB, XOR-swizzled bf16

    const int t = threadIdx.x;
    const int w = t >> 6, lane = t & 63;
    const int m = lane & 15, q = lane >> 4;
    const int mb = blockIdx.x >> 1, nb = blockIdx.x & 1;
    const int bm = mb * 32;            // 625 m-blocks, exact (20000 = 625*32)
    const int nb128 = nb * 128;

    // A global staging (coalesced): thread t covers rows (t>>5)+8s, s=0..3,
    // 16 B at column (t&31)*16 within the 512 B chunk-row.
    const int ar = t >> 5;             // 0..7
    const int ac = (t & 31) * 4;       // float offset 0..124
    const float* gA = Xf + (size_t)(bm + ar) * K_DIM + ac;

    // A LDS write/read offsets
    const int aw_base = ar * AROW + ac;           // + s*8*AROW per s

    // B staging: 8 issues/thread/chunk (XOR-swizzled slots)
    int bn[8], bcc[8], bdst[8];
#pragma unroll
    for (int i = 0; i < 8; ++i) {
        int L = i * 256 + t;
        bn[i] = L >> 4;
        int cp = L & 15;
        bcc[i] = cp ^ (bn[i] & 15);
        bdst[i] = (i * 256 + w * 64) * 16;
    }

    f32x4 acc[2][2];
#pragma unroll
    for (int i = 0; i < 2; ++i)
#pragma unroll
        for (int j = 0; j < 2; ++j)
            acc[i][j] = (f32x4){0.f, 0.f, 0.f, 0.f};

    float4 ar0[4], ar1[4];   // two A register sets (chunk parity)

    // ---- prologue ----
#pragma unroll
    for (int s = 0; s < 4; ++s)                       // A(0) -> set0
        ar0[s] = *(const float4*)(gA + (size_t)s * 8 * K_DIM);
#pragma unroll
    for (int i = 0; i < 8; ++i)                       // B(0) -> LDS
        __builtin_amdgcn_global_load_lds(AS1(Wt + (size_t)(nb128 + bn[i]) * K_DIM + bcc[i] * 8),
                                         AS3((char*)Bs + bdst[i]), 16, 0, 0);
#pragma unroll
    for (int s = 0; s < 4; ++s)                       // A(0) regs -> LDS
        *(float4*)(As + aw_base + s * 8 * AROW) = ar0[s];
#pragma unroll
    for (int s = 0; s < 4; ++s)                       // A(1) -> set1
        ar1[s] = *(const float4*)(gA + 128 + (size_t)s * 8 * K_DIM);
    __syncthreads();

#pragma unroll
    for (int c = 0; c < NCHUNK; ++c) {
        // issue A(c+2) into the set freed by last chunk's ds_write
        if (c + 2 < NCHUNK) {
            const int kc2 = (c + 2) * 128;
            if ((c & 1) == 0) {
#pragma unroll
                for (int s = 0; s < 4; ++s)
                    ar0[s] = *(const float4*)(gA + kc2 + (size_t)s * 8 * K_DIM);
            } else {
#pragma unroll
                for (int s = 0; s < 4; ++s)
                    ar1[s] = *(const float4*)(gA + kc2 + (size_t)s * 8 * K_DIM);
            }
        }
        // compute chunk c: 4 k-steps x (2 i-tiles x 2 j-tiles)
#pragma unroll
        for (int ks = 0; ks < 4; ++ks) {
            bf16x8 aF[2], bF[2];
#pragma unroll
            for (int i = 0; i < 2; ++i) {
                const float* ap = As + (m + 16 * i) * AROW + ks * 32 + q * 8;
                float4 u = *(const float4*)ap;
                float4 v = *(const float4*)(ap + 4);
                aF[i] = cvt8(u, v);
            }
#pragma unroll
            for (int j = 0; j < 2; ++j) {
                int n_loc = w * 32 + j * 16 + m;
                bF[j] = *(const bf16x8*)((const char*)Bs + n_loc * 256 + (((ks * 4 + q) ^ m) * 16));
            }
#pragma unroll
            for (int i = 0; i < 2; ++i)
#pragma unroll
                for (int j = 0; j < 2; ++j)
                    acc[i][j] = __builtin_amdgcn_mfma_f32_16x16x32_bf16(aF[i], bF[j], acc[i][j], 0, 0, 0);
        }
        __syncthreads();                       // done reading As, Bs
        if (c + 1 < NCHUNK) {
            // A(c+1) regs -> LDS
            if ((c & 1) == 0) {
#pragma unroll
                for (int s = 0; s < 4; ++s)
                    *(float4*)(As + aw_base + s * 8 * AROW) = ar1[s];
            } else {
#pragma unroll
                for (int s = 0; s < 4; ++s)
                    *(float4*)(As + aw_base + s * 8 * AROW) = ar0[s];
            }
            // B(c+1) -> LDS
            const int kc = (c + 1) * 128;
#pragma unroll
            for (int i = 0; i < 8; ++i)
                __builtin_amdgcn_global_load_lds(
                    AS1(Wt + (size_t)(nb128 + bn[i]) * K_DIM + kc + bcc[i] * 8),
                    AS3((char*)Bs + bdst[i]), 16, 0, 0);
            __syncthreads();                   // publish chunk c+1
        }
    }

    // ---- epilogue: row = bm + i*16 + q*4 + r; col = w*32 + j*16 + m ----
    float* __restrict__ Y = nb ? t_lin : y_tl;
#pragma unroll
    for (int i = 0; i < 2; ++i) {
#pragma unroll
        for (int j = 0; j < 2; ++j) {
            int col = w * 32 + j * 16 + m;
#pragma unroll
            for (int r = 0; r < 4; ++r) {
                int row = bm + i * 16 + q * 4 + r;
                Y[(size_t)row * H + col] = acc[i][j][r];
            }
        }
    }
}

// ---- target post (wave per target): gather agg + linear + relu + dot ------
__global__ void target_post(const int* __restrict__ cur_t, const int* __restrict__ adjs,
                            const float* __restrict__ xl, const float* __restrict__ t_lin,
                            const float* __restrict__ W_lt_l, const float* __restrict__ b_lt_l,
                            const float* __restrict__ W_ep,
                            float* __restrict__ st, int NT)
{
    int wid = (blockIdx.x * blockDim.x + threadIdx.x) >> 6;
    int lane = threadIdx.x & 63;
    if (wid >= NT) return;
    int cnt = cur_t[wid];
    float a0 = 0.f, a1 = 0.f, a2 = 0.f, a3 = 0.f;
    for (int j = lane; j < cnt; j += 64) {
        int s = adjs[wid * CAP_T + j];
        float4 v = *(const float4*)(xl + (size_t)s * LIG_IN);
        a0 += v.x; a1 += v.y; a2 += v.z; a3 += v.w;
    }
#pragma unroll
    for (int off = 32; off > 0; off >>= 1) {
        a0 += __shfl_xor(a0, off);
        a1 += __shfl_xor(a1, off);
        a2 += __shfl_xor(a2, off);
        a3 += __shfl_xor(a3, off);
    }
    float inv = 1.0f / fmaxf((float)cnt, 1.0f);
    a0 *= inv; a1 *= inv; a2 *= inv; a3 *= inv;
    float acc = 0.f;
#pragma unroll
    for (int p = 0; p < 2; ++p) {
        int h = lane + p * 64;
        float v = a0 * W_lt_l[h] + a1 * W_lt_l[H + h] + a2 * W_lt_l[2 * H + h] +
                  a3 * W_lt_l[3 * H + h] + b_lt_l[h] + t_lin[(size_t)wid * H + h];
        v = fmaxf(v, 0.f);
        acc += v * W_ep[H + h];
    }
#pragma unroll
    for (int off = 32; off > 0; off >>= 1) acc += __shfl_down(acc, off);
    if (lane == 0) st[wid] = acc;
}

// ---- fused ligand gather + post (wave per ligand) -------------------------
__global__ void ligand_gather_post(const int* __restrict__ cur_l, const int* __restrict__ adjd,
                                   const float* __restrict__ y_tl,
                                   const float* __restrict__ xl,
                                   const float* __restrict__ W_tl_r, const float* __restrict__ b_tl_l,
                                   const float* __restrict__ W_ep,
                                   float* __restrict__ sl, int NL)
{
    int wid = (blockIdx.x * blockDim.x + threadIdx.x) >> 6;
    int lane = threadIdx.x & 63;
    if (wid >= NL) return;
    int cnt = cur_l[wid];
    float a0 = 0.f, a1 = 0.f;   // h = 2*lane, 2*lane+1
    for (int j = 0; j < cnt; ++j) {
        int d = adjd[wid * CAP_L + j];
        float2 f = ((const float2*)(y_tl + (size_t)d * H))[lane];  // one 512B row load
        a0 += f.x;
        a1 += f.y;
    }
    float inv = 1.0f / fmaxf((float)cnt, 1.0f);
    float4 x = *(const float4*)(xl + (size_t)wid * LIG_IN);
    float acc = 0.f;
    {
        int h = 2 * lane;
        float v = a0 * inv + b_tl_l[h] +
                  x.x * W_tl_r[h] + x.y * W_tl_r[H + h] +
                  x.z * W_tl_r[2 * H + h] + x.w * W_tl_r[3 * H + h];
        v = fmaxf(v, 0.f);
        acc += v * W_ep[h];
    }
    {
        int h = 2 * lane + 1;
        float v = a1 * inv + b_tl_l[h] +
                  x.x * W_tl_r[h] + x.y * W_tl_r[H + h] +
                  x.z * W_tl_r[2 * H + h] + x.w * W_tl_r[3 * H + h];
        v = fmaxf(v, 0.f);
        acc += v * W_ep[h];
    }
#pragma unroll
    for (int off = 32; off > 0; off >>= 1) acc += __shfl_down(acc, off);
    if (lane == 0) sl[wid] = acc;
}

// ---- final edge output ----------------------------------------------------
__global__ void edge_out(const int* __restrict__ src, const int* __restrict__ dst,
                         const float* __restrict__ sl, const float* __restrict__ st,
                         const float* __restrict__ b_ep, float* __restrict__ out, int E)
{
    int e = blockIdx.x * blockDim.x + threadIdx.x;
    if (e >= E) return;
    out[e] = sl[src[e]] + st[dst[e]] + b_ep[0];
}

// ---------------------------------------------------------------------------
extern "C" void kernel_launch(void* const* d_in, const int* in_sizes, int n_in,
                              void* d_out, int out_size, void* d_ws, size_t ws_size,
                              hipStream_t stream) {
    const float* x_ligand = (const float*)d_in[0];
    const float* x_target = (const float*)d_in[1];
    const int*   edge_src = (const int*)d_in[2];
    const int*   edge_dst = (const int*)d_in[3];
    const float* W_lt_l   = (const float*)d_in[4];
    const float* b_lt_l   = (const float*)d_in[5];
    const float* W_lt_r   = (const float*)d_in[6];
    const float* W_tl_l   = (const float*)d_in[7];
    const float* b_tl_l   = (const float*)d_in[8];
    const float* W_tl_r   = (const float*)d_in[9];
    const float* W_ep     = (const float*)d_in[10];
    const float* b_ep     = (const float*)d_in[11];
    float* out = (float*)d_out;

    const int NL = in_sizes[0] / LIG_IN;   // 100000
    const int NT = in_sizes[1] / K_DIM;    // 20000
    const int E  = in_sizes[2];            // 250000

    // ---- workspace layout (16B-aligned offsets) ----
    char* ws = (char*)d_ws;
    size_t off = 0;
    auto take = [&](size_t bytes) { size_t o = off; off += (bytes + 15) & ~(size_t)15; return o; };
    size_t off_Wt     = take((size_t)2 * H * K_DIM * 2); // 655 KB bf16
    size_t off_y_tl   = take((size_t)NT * H * 4);        // 10.24 MB
    size_t off_t_lin  = take((size_t)NT * H * 4);        // 10.24 MB
    size_t off_adjd   = take((size_t)NL * CAP_L * 4);    // 9.6 MB
    size_t off_adjs   = take((size_t)NT * CAP_T * 4);    // 3.84 MB
    size_t off_cur_l  = take((size_t)NL * 4);            // <- memset start
    size_t off_cur_t  = take((size_t)NT * 4);            // <- memset end
    size_t off_sl     = take((size_t)NL * 4);
    size_t off_st     = take((size_t)NT * 4);
    if (off > ws_size) {
        hipMemsetAsync(d_out, 0, (size_t)out_size * 4, stream);
        return;
    }

    __hip_bfloat16* Wt = (__hip_bfloat16*)(ws + off_Wt);
    float* y_tl  = (float*)(ws + off_y_tl);
    float* t_lin = (float*)(ws + off_t_lin);
    int*   adjd  = (int*)(ws + off_adjd);
    int*   adjs  = (int*)(ws + off_adjs);
    int*   cur_l = (int*)(ws + off_cur_l);
    int*   cur_t = (int*)(ws + off_cur_t);
    float* sl    = (float*)(ws + off_sl);
    float* st    = (float*)(ws + off_st);

    // zero the cursors (contiguous)
    hipMemsetAsync(cur_l, 0, off_sl - off_cur_l, stream);

    // 1. weight cast (GEMM needs it first)
    int nw = 2 * H * K_DIM;
    cast_wt<<<(nw + 255) / 256, 256, 0, stream>>>(W_tl_l, W_lt_r, Wt, nw);

    // 2. GEMM: grid 1250 (mb = bid>>1, nb = bid&1)
    gemm_fused<<<(NT / 32) * 2, 256, 0, stream>>>(x_target, (const unsigned short*)Wt,
                                                  y_tl, t_lin, NT);

    // 3. adjacency build (1 atomic per edge per side)
    fill_both<<<(E + 255) / 256, 256, 0, stream>>>(edge_src, edge_dst,
                                                   cur_l, cur_t, adjd, adjs, E);

    // 4. target post -> st (gathers x_ligand via adjs)
    target_post<<<(NT * 64 + 255) / 256, 256, 0, stream>>>(cur_t, adjs, x_ligand, t_lin,
                                                           W_lt_l, b_lt_l, W_ep, st, NT);
    // 5. ligand gather + post -> sl
    ligand_gather_post<<<(NL * 64 + 255) / 256, 256, 0, stream>>>(cur_l, adjd, y_tl, x_ligand,
                                                                  W_tl_r, b_tl_l, W_ep, sl, NL);
    // 6. edge output
    edge_out<<<(E + 255) / 256, 256, 0, stream>>>(edge_src, edge_dst, sl, st, b_ep, out, E);
}

// Round 11
// 356.939 us; speedup vs baseline: 1.0269x; 1.0269x over previous
//
#include <hip/hip_runtime.h>
#include <hip/hip_bf16.h>

// ---------------------------------------------------------------------------
// HeteroGNN forward (round 11):
//   - GEMM: NO LDS, NO barriers. B pre-swizzled frag-major by cast_wt so each
//     B fragment is one coalesced 1KB dwordx4 load from L2-hot 655KB weights.
//     A: f32 global->register->bf16, 1-step static prefetch. Each wave owns
//     32 rows x 128 cols; waves fully independent (hardware scoreboard only).
//   - fixed-capacity adjacency, gather-based aggregation, fused posts
// ---------------------------------------------------------------------------

#define H 128
#define K_DIM 1280
#define LIG_IN 4
#define CAP_L 24    // max ligand degree (lambda=2.5; observed max ~13)
#define CAP_T 48    // max target degree (lambda=12.5; observed max ~34)
#define NSTEP 40    // K_DIM / 32

typedef __attribute__((ext_vector_type(8))) short bf16x8;
typedef __attribute__((ext_vector_type(4))) float f32x4;

// ---- kernel 1: build both fixed-capacity adjacencies ----------------------
__global__ void fill_both(const int* __restrict__ src, const int* __restrict__ dst,
                          int* __restrict__ cur_l, int* __restrict__ cur_t,
                          int* __restrict__ adjd, int* __restrict__ adjs, int E)
{
    int e = blockIdx.x * blockDim.x + threadIdx.x;
    if (e >= E) return;
    int s = src[e], d = dst[e];
    int p = atomicAdd(&cur_l[s], 1);
    adjd[s * CAP_L + p] = d;
    int q = atomicAdd(&cur_t[d], 1);
    adjs[d * CAP_T + q] = s;
}

// ---- cast weights into FRAG-MAJOR layout ----------------------------------
// dest element for source (n,k):  jt=n>>4, m=n&15, s=k>>5, q=(k>>3)&3, e=k&7
//   Wf[ ((jt*40 + s)*64 + q*16 + m)*8 + e ]
// so a wave's B fragment (jt,s) = 64 lanes x 16B contiguous (1KB coalesced).
__global__ void cast_wt(const float* __restrict__ Wl, const float* __restrict__ Wr,
                        __hip_bfloat16* __restrict__ Wf, int total)
{
    int idx = blockIdx.x * blockDim.x + threadIdx.x;
    if (idx >= total) return;
    int n = idx / K_DIM, k = idx - n * K_DIM;
    float v = (n < H) ? Wl[k * H + n] : Wr[k * H + (n - H)];
    int jt = n >> 4, m = n & 15;
    int s = k >> 5, q = (k >> 3) & 3, e = k & 7;
    Wf[(size_t)(((jt * NSTEP + s) * 64) + q * 16 + m) * 8 + e] = __float2bfloat16(v);
}

// ---- GEMM: [M,1280] f32 @ [1280,256] bf16 -> y_tl | t_lin (f32) -----------
__device__ inline bf16x8 cvt8(float4 u, float4 v)
{
    union { __hip_bfloat16 h[8]; bf16x8 f; } r;
    r.h[0] = __float2bfloat16(u.x); r.h[1] = __float2bfloat16(u.y);
    r.h[2] = __float2bfloat16(u.z); r.h[3] = __float2bfloat16(u.w);
    r.h[4] = __float2bfloat16(v.x); r.h[5] = __float2bfloat16(v.y);
    r.h[6] = __float2bfloat16(v.z); r.h[7] = __float2bfloat16(v.w);
    return r.f;
}

__global__ __launch_bounds__(256)
void gemm_fused(const float* __restrict__ Xf,          // [M,1280] f32
                const unsigned short* __restrict__ Wf, // frag-major bf16
                float* __restrict__ y_tl, float* __restrict__ t_lin, int M)
{
    const int t = threadIdx.x;
    const int w = t >> 6, lane = t & 63;
    const int m = lane & 15, q = lane >> 4;
    const int mb = blockIdx.x >> 1, nb = blockIdx.x & 1;
    const int bm = mb * 128;                 // block: 128 rows; wave: 32 rows
    const int wrow = bm + w * 32;

    // A rows for this lane's two i-tiles (clamped for the 157th block)
    const int r0 = min(wrow + m, M - 1);
    const int r1 = min(wrow + 16 + m, M - 1);
    const float* gA0 = Xf + (size_t)r0 * K_DIM + q * 8;
    const float* gA1 = Xf + (size_t)r1 * K_DIM + q * 8;

    // B fragment stream base: jt = nb*8 + j; frag(jt,s) at ((jt*40+s)*64+lane)*8
    const unsigned short* gB = Wf + (size_t)((nb * 8) * NSTEP * 64 + lane) * 8;

    f32x4 acc[2][8];
#pragma unroll
    for (int i = 0; i < 2; ++i)
#pragma unroll
        for (int j = 0; j < 8; ++j)
            acc[i][j] = (f32x4){0.f, 0.f, 0.f, 0.f};

    float4 aA[2][2][2];      // [parity][i][half]
    bf16x8 bB[2][8];         // [parity][j]

    // ---- preload step 0 into parity 0 ----
    aA[0][0][0] = *(const float4*)(gA0);
    aA[0][0][1] = *(const float4*)(gA0 + 4);
    aA[0][1][0] = *(const float4*)(gA1);
    aA[0][1][1] = *(const float4*)(gA1 + 4);
#pragma unroll
    for (int j = 0; j < 8; ++j)
        bB[0][j] = *(const bf16x8*)(gB + (size_t)(j * NSTEP) * 64 * 8);

#pragma unroll
    for (int s = 0; s < NSTEP; ++s) {
        const int cur = s & 1, nxt = cur ^ 1;
        if (s + 1 < NSTEP) {
            const int k1 = (s + 1) * 32;
            aA[nxt][0][0] = *(const float4*)(gA0 + k1);
            aA[nxt][0][1] = *(const float4*)(gA0 + k1 + 4);
            aA[nxt][1][0] = *(const float4*)(gA1 + k1);
            aA[nxt][1][1] = *(const float4*)(gA1 + k1 + 4);
#pragma unroll
            for (int j = 0; j < 8; ++j)
                bB[nxt][j] = *(const bf16x8*)(gB + (size_t)(j * NSTEP + s + 1) * 64 * 8);
        }
        bf16x8 aF0 = cvt8(aA[cur][0][0], aA[cur][0][1]);
        bf16x8 aF1 = cvt8(aA[cur][1][0], aA[cur][1][1]);
#pragma unroll
        for (int j = 0; j < 8; ++j) {
            acc[0][j] = __builtin_amdgcn_mfma_f32_16x16x32_bf16(aF0, bB[cur][j], acc[0][j], 0, 0, 0);
            acc[1][j] = __builtin_amdgcn_mfma_f32_16x16x32_bf16(aF1, bB[cur][j], acc[1][j], 0, 0, 0);
        }
    }

    // ---- epilogue: row = wrow + i*16 + q*4 + r; col = j*16 + m ----
    float* __restrict__ Y = nb ? t_lin : y_tl;
#pragma unroll
    for (int i = 0; i < 2; ++i) {
#pragma unroll
        for (int j = 0; j < 8; ++j) {
            int col = j * 16 + m;
#pragma unroll
            for (int r = 0; r < 4; ++r) {
                int row = wrow + i * 16 + q * 4 + r;
                if (row < M) Y[(size_t)row * H + col] = acc[i][j][r];
            }
        }
    }
}

// ---- target post (wave per target): gather agg + linear + relu + dot ------
__global__ void target_post(const int* __restrict__ cur_t, const int* __restrict__ adjs,
                            const float* __restrict__ xl, const float* __restrict__ t_lin,
                            const float* __restrict__ W_lt_l, const float* __restrict__ b_lt_l,
                            const float* __restrict__ W_ep,
                            float* __restrict__ st, int NT)
{
    int wid = (blockIdx.x * blockDim.x + threadIdx.x) >> 6;
    int lane = threadIdx.x & 63;
    if (wid >= NT) return;
    int cnt = cur_t[wid];
    float a0 = 0.f, a1 = 0.f, a2 = 0.f, a3 = 0.f;
    for (int j = lane; j < cnt; j += 64) {
        int s = adjs[wid * CAP_T + j];
        float4 v = *(const float4*)(xl + (size_t)s * LIG_IN);
        a0 += v.x; a1 += v.y; a2 += v.z; a3 += v.w;
    }
#pragma unroll
    for (int off = 32; off > 0; off >>= 1) {
        a0 += __shfl_xor(a0, off);
        a1 += __shfl_xor(a1, off);
        a2 += __shfl_xor(a2, off);
        a3 += __shfl_xor(a3, off);
    }
    float inv = 1.0f / fmaxf((float)cnt, 1.0f);
    a0 *= inv; a1 *= inv; a2 *= inv; a3 *= inv;
    float acc = 0.f;
#pragma unroll
    for (int p = 0; p < 2; ++p) {
        int h = lane + p * 64;
        float v = a0 * W_lt_l[h] + a1 * W_lt_l[H + h] + a2 * W_lt_l[2 * H + h] +
                  a3 * W_lt_l[3 * H + h] + b_lt_l[h] + t_lin[(size_t)wid * H + h];
        v = fmaxf(v, 0.f);
        acc += v * W_ep[H + h];
    }
#pragma unroll
    for (int off = 32; off > 0; off >>= 1) acc += __shfl_down(acc, off);
    if (lane == 0) st[wid] = acc;
}

// ---- fused ligand gather + post (wave per ligand) -------------------------
__global__ void ligand_gather_post(const int* __restrict__ cur_l, const int* __restrict__ adjd,
                                   const float* __restrict__ y_tl,
                                   const float* __restrict__ xl,
                                   const float* __restrict__ W_tl_r, const float* __restrict__ b_tl_l,
                                   const float* __restrict__ W_ep,
                                   float* __restrict__ sl, int NL)
{
    int wid = (blockIdx.x * blockDim.x + threadIdx.x) >> 6;
    int lane = threadIdx.x & 63;
    if (wid >= NL) return;
    int cnt = cur_l[wid];
    float a0 = 0.f, a1 = 0.f;   // h = 2*lane, 2*lane+1
    for (int j = 0; j < cnt; ++j) {
        int d = adjd[wid * CAP_L + j];
        float2 f = ((const float2*)(y_tl + (size_t)d * H))[lane];  // one 512B row load
        a0 += f.x;
        a1 += f.y;
    }
    float inv = 1.0f / fmaxf((float)cnt, 1.0f);
    float4 x = *(const float4*)(xl + (size_t)wid * LIG_IN);
    float acc = 0.f;
    {
        int h = 2 * lane;
        float v = a0 * inv + b_tl_l[h] +
                  x.x * W_tl_r[h] + x.y * W_tl_r[H + h] +
                  x.z * W_tl_r[2 * H + h] + x.w * W_tl_r[3 * H + h];
        v = fmaxf(v, 0.f);
        acc += v * W_ep[h];
    }
    {
        int h = 2 * lane + 1;
        float v = a1 * inv + b_tl_l[h] +
                  x.x * W_tl_r[h] + x.y * W_tl_r[H + h] +
                  x.z * W_tl_r[2 * H + h] + x.w * W_tl_r[3 * H + h];
        v = fmaxf(v, 0.f);
        acc += v * W_ep[h];
    }
#pragma unroll
    for (int off = 32; off > 0; off >>= 1) acc += __shfl_down(acc, off);
    if (lane == 0) sl[wid] = acc;
}

// ---- final edge output ----------------------------------------------------
__global__ void edge_out(const int* __restrict__ src, const int* __restrict__ dst,
                         const float* __restrict__ sl, const float* __restrict__ st,
                         const float* __restrict__ b_ep, float* __restrict__ out, int E)
{
    int e = blockIdx.x * blockDim.x + threadIdx.x;
    if (e >= E) return;
    out[e] = sl[src[e]] + st[dst[e]] + b_ep[0];
}

// ---------------------------------------------------------------------------
extern "C" void kernel_launch(void* const* d_in, const int* in_sizes, int n_in,
                              void* d_out, int out_size, void* d_ws, size_t ws_size,
                              hipStream_t stream) {
    const float* x_ligand = (const float*)d_in[0];
    const float* x_target = (const float*)d_in[1];
    const int*   edge_src = (const int*)d_in[2];
    const int*   edge_dst = (const int*)d_in[3];
    const float* W_lt_l   = (const float*)d_in[4];
    const float* b_lt_l   = (const float*)d_in[5];
    const float* W_lt_r   = (const float*)d_in[6];
    const float* W_tl_l   = (const float*)d_in[7];
    const float* b_tl_l   = (const float*)d_in[8];
    const float* W_tl_r   = (const float*)d_in[9];
    const float* W_ep     = (const float*)d_in[10];
    const float* b_ep     = (const float*)d_in[11];
    float* out = (float*)d_out;

    const int NL = in_sizes[0] / LIG_IN;   // 100000
    const int NT = in_sizes[1] / K_DIM;    // 20000
    const int E  = in_sizes[2];            // 250000

    // ---- workspace layout (16B-aligned offsets) ----
    char* ws = (char*)d_ws;
    size_t off = 0;
    auto take = [&](size_t bytes) { size_t o = off; off += (bytes + 15) & ~(size_t)15; return o; };
    size_t off_Wt     = take((size_t)2 * H * K_DIM * 2); // 655 KB bf16 (frag-major)
    size_t off_y_tl   = take((size_t)NT * H * 4);        // 10.24 MB
    size_t off_t_lin  = take((size_t)NT * H * 4);        // 10.24 MB
    size_t off_adjd   = take((size_t)NL * CAP_L * 4);    // 9.6 MB
    size_t off_adjs   = take((size_t)NT * CAP_T * 4);    // 3.84 MB
    size_t off_cur_l  = take((size_t)NL * 4);            // <- memset start
    size_t off_cur_t  = take((size_t)NT * 4);            // <- memset end
    size_t off_sl     = take((size_t)NL * 4);
    size_t off_st     = take((size_t)NT * 4);
    if (off > ws_size) {
        hipMemsetAsync(d_out, 0, (size_t)out_size * 4, stream);
        return;
    }

    __hip_bfloat16* Wt = (__hip_bfloat16*)(ws + off_Wt);
    float* y_tl  = (float*)(ws + off_y_tl);
    float* t_lin = (float*)(ws + off_t_lin);
    int*   adjd  = (int*)(ws + off_adjd);
    int*   adjs  = (int*)(ws + off_adjs);
    int*   cur_l = (int*)(ws + off_cur_l);
    int*   cur_t = (int*)(ws + off_cur_t);
    float* sl    = (float*)(ws + off_sl);
    float* st    = (float*)(ws + off_st);

    // zero the cursors (contiguous)
    hipMemsetAsync(cur_l, 0, off_sl - off_cur_l, stream);

    // 1. weight cast into frag-major layout
    int nw = 2 * H * K_DIM;
    cast_wt<<<(nw + 255) / 256, 256, 0, stream>>>(W_tl_l, W_lt_r, Wt, nw);

    // 2. GEMM: grid 157*2 (mb = bid>>1, nb = bid&1), no LDS, no barriers
    gemm_fused<<<((NT + 127) / 128) * 2, 256, 0, stream>>>(x_target, (const unsigned short*)Wt,
                                                           y_tl, t_lin, NT);

    // 3. adjacency build (1 atomic per edge per side)
    fill_both<<<(E + 255) / 256, 256, 0, stream>>>(edge_src, edge_dst,
                                                   cur_l, cur_t, adjd, adjs, E);

    // 4. target post -> st (gathers x_ligand via adjs)
    target_post<<<(NT * 64 + 255) / 256, 256, 0, stream>>>(cur_t, adjs, x_ligand, t_lin,
                                                           W_lt_l, b_lt_l, W_ep, st, NT);
    // 5. ligand gather + post -> sl
    ligand_gather_post<<<(NL * 64 + 255) / 256, 256, 0, stream>>>(cur_l, adjd, y_tl, x_ligand,
                                                                  W_tl_r, b_tl_l, W_ep, sl, NL);
    // 6. edge output
    edge_out<<<(E + 255) / 256, 256, 0, stream>>>(edge_src, edge_dst, sl, st, b_ep, out, E);
}

// Round 12
// 297.543 us; speedup vs baseline: 1.2318x; 1.1996x over previous
//
#include <hip/hip_runtime.h>
#include <hip/hip_bf16.h>

// ---------------------------------------------------------------------------
// HeteroGNN forward (round 12):
//   - GEMM: BOTH A and B staged via global_load_lds DMA with the XOR swizzle
//     baked into the per-lane GLOBAL source address (LDS dst is lane*16B,
//     layout fixed): A slot16B = m*16+(c^(m&15)) [f32], B slot = n*8+(c^(n&7))
//     [bf16]. All ds_read_b128 patterns are 2-way (free). A is finally
//     COALESCED (R5-R11 were A-scatter-bound at ~1-1.7 TB/s: lane=row).
//     BM=64 BN=128 BK=64, 32KB LDS, grid 626, wave tile 32x64 (acc[2][4]).
//   - fixed-capacity adjacency, gather-based aggregation, fused posts
// ---------------------------------------------------------------------------

#define H 128
#define K_DIM 1280
#define LIG_IN 4
#define CAP_L 24    // max ligand degree (lambda=2.5; observed max ~13)
#define CAP_T 48    // max target degree (lambda=12.5; observed max ~34)
#define NCH 20      // K_DIM / 64

typedef __attribute__((ext_vector_type(8))) short bf16x8;
typedef __attribute__((ext_vector_type(4))) float f32x4;

#define AS1(p) ((const __attribute__((address_space(1))) void*)(p))
#define AS3(p) ((__attribute__((address_space(3))) void*)(p))

// ---- kernel 1: build both fixed-capacity adjacencies ----------------------
__global__ void fill_both(const int* __restrict__ src, const int* __restrict__ dst,
                          int* __restrict__ cur_l, int* __restrict__ cur_t,
                          int* __restrict__ adjd, int* __restrict__ adjs, int E)
{
    int e = blockIdx.x * blockDim.x + threadIdx.x;
    if (e >= E) return;
    int s = src[e], d = dst[e];
    int p = atomicAdd(&cur_l[s], 1);
    adjd[s * CAP_L + p] = d;
    int q = atomicAdd(&cur_t[d], 1);
    adjs[d * CAP_T + q] = s;
}

// ---- cast weights: Wt[n][k]; n<128 -> W_tl_l (y_tl), n>=128 -> W_lt_r -----
__global__ void cast_wt(const float* __restrict__ Wl, const float* __restrict__ Wr,
                        __hip_bfloat16* __restrict__ Wt, int n)
{
    int idx = blockIdx.x * blockDim.x + threadIdx.x;
    if (idx >= n) return;
    int nr = idx / K_DIM, k = idx - nr * K_DIM;
    float v = (nr < H) ? Wl[k * H + nr] : Wr[k * H + (nr - H)];
    Wt[idx] = __float2bfloat16(v);
}

// ---- GEMM: [M,1280] f32 @ [1280,256] bf16 -> y_tl | t_lin (f32) -----------
__device__ inline bf16x8 cvt8(float4 u, float4 v)
{
    union { __hip_bfloat16 h[8]; bf16x8 f; } r;
    r.h[0] = __float2bfloat16(u.x); r.h[1] = __float2bfloat16(u.y);
    r.h[2] = __float2bfloat16(u.z); r.h[3] = __float2bfloat16(u.w);
    r.h[4] = __float2bfloat16(v.x); r.h[5] = __float2bfloat16(v.y);
    r.h[6] = __float2bfloat16(v.z); r.h[7] = __float2bfloat16(v.w);
    return r.f;
}

__global__ __launch_bounds__(256)
void gemm_fused(const float* __restrict__ Xf,          // [M,1280] f32
                const unsigned short* __restrict__ Wt, // [256,1280] bf16 n-major
                float* __restrict__ y_tl, float* __restrict__ t_lin, int M)
{
    __shared__ float As[64 * 64];   // 16 KB; 16B-slot = m*16 + (c ^ (m&15))
    __shared__ short Bs[128 * 64];  // 16 KB; 16B-slot = n*8 + (c ^ (n&7))

    const int t = threadIdx.x;
    const int w = t >> 6, lane = t & 63;
    const int m16 = lane & 15, q = lane >> 4;
    const int wm = w & 1, wn = w >> 1;          // 2x2 wave grid
    const int mb = blockIdx.x >> 1, nb = blockIdx.x & 1;
    const int bm = mb * 64;
    const int nb128 = nb * 128;

    // ---- staging address setup (per-lane swizzled global source) ----
    // A: 1024 slots (64 rows x 16 chunks of 16B); 4 DMA instrs/wave/chunk
    const float* a_g[4];
#pragma unroll
    for (int i = 0; i < 4; ++i) {
        int slot = i * 256 + w * 64 + lane;
        int m = slot >> 4, cl = slot & 15;
        int cg = cl ^ (m & 15);
        int row = min(bm + m, M - 1);
        a_g[i] = Xf + (size_t)row * K_DIM + cg * 4;
    }
    // B: 1024 slots (128 rows x 8 chunks of 16B)
    const unsigned short* b_g[4];
#pragma unroll
    for (int i = 0; i < 4; ++i) {
        int slot = i * 256 + w * 64 + lane;
        int n = slot >> 3, cl = slot & 7;
        int cg = cl ^ (n & 7);
        b_g[i] = Wt + (size_t)(nb128 + n) * K_DIM + cg * 8;
    }

    f32x4 acc[2][4];
#pragma unroll
    for (int i = 0; i < 2; ++i)
#pragma unroll
        for (int j = 0; j < 4; ++j)
            acc[i][j] = (f32x4){0.f, 0.f, 0.f, 0.f};

    // ---- stage chunk 0 ----
#pragma unroll
    for (int i = 0; i < 4; ++i)
        __builtin_amdgcn_global_load_lds(AS1(a_g[i]), AS3((char*)As + (i * 256 + w * 64) * 16), 16, 0, 0);
#pragma unroll
    for (int i = 0; i < 4; ++i)
        __builtin_amdgcn_global_load_lds(AS1(b_g[i]), AS3((char*)Bs + (i * 256 + w * 64) * 16), 16, 0, 0);
    __syncthreads();

    for (int ch = 0; ch < NCH; ++ch) {
        // compute chunk ch (2 k-steps of 32)
#pragma unroll
        for (int ks = 0; ks < 2; ++ks) {
            bf16x8 aF[2];
#pragma unroll
            for (int i = 0; i < 2; ++i) {
                int row = wm * 32 + i * 16 + m16;
                int c = ks * 8 + q * 2;
                int s0 = row * 16 + (c ^ m16);        // row&15 == m16
                int s1 = s0 ^ 1;                      // chunk c|1
                float4 u = *(const float4*)((const char*)As + s0 * 16);
                float4 v = *(const float4*)((const char*)As + s1 * 16);
                aF[i] = cvt8(u, v);
            }
            bf16x8 bF[4];
#pragma unroll
            for (int j = 0; j < 4; ++j) {
                int n = wn * 64 + j * 16 + m16;
                int c = ks * 4 + q;
                int s = n * 8 + (c ^ (n & 7));
                bF[j] = *(const bf16x8*)((const char*)Bs + s * 16);
            }
#pragma unroll
            for (int i = 0; i < 2; ++i)
#pragma unroll
                for (int j = 0; j < 4; ++j)
                    acc[i][j] = __builtin_amdgcn_mfma_f32_16x16x32_bf16(aF[i], bF[j], acc[i][j], 0, 0, 0);
        }
        __syncthreads();                    // done reading chunk ch
        if (ch + 1 < NCH) {
            const int kc = (ch + 1) * 64;   // offset in elements (f32 / bf16)
#pragma unroll
            for (int i = 0; i < 4; ++i)
                __builtin_amdgcn_global_load_lds(AS1(a_g[i] + kc),
                                                 AS3((char*)As + (i * 256 + w * 64) * 16), 16, 0, 0);
#pragma unroll
            for (int i = 0; i < 4; ++i)
                __builtin_amdgcn_global_load_lds(AS1(b_g[i] + kc),
                                                 AS3((char*)Bs + (i * 256 + w * 64) * 16), 16, 0, 0);
            __syncthreads();                // publish chunk ch+1
        }
    }

    // ---- epilogue: row = bm + wm*32 + i*16 + q*4 + r; col = wn*64 + j*16 + m16
    float* __restrict__ Y = nb ? t_lin : y_tl;
#pragma unroll
    for (int i = 0; i < 2; ++i) {
#pragma unroll
        for (int j = 0; j < 4; ++j) {
            int col = wn * 64 + j * 16 + m16;
#pragma unroll
            for (int r = 0; r < 4; ++r) {
                int row = bm + wm * 32 + i * 16 + q * 4 + r;
                if (row < M) Y[(size_t)row * H + col] = acc[i][j][r];
            }
        }
    }
}

// ---- target post (wave per target): gather agg + linear + relu + dot ------
__global__ void target_post(const int* __restrict__ cur_t, const int* __restrict__ adjs,
                            const float* __restrict__ xl, const float* __restrict__ t_lin,
                            const float* __restrict__ W_lt_l, const float* __restrict__ b_lt_l,
                            const float* __restrict__ W_ep,
                            float* __restrict__ st, int NT)
{
    int wid = (blockIdx.x * blockDim.x + threadIdx.x) >> 6;
    int lane = threadIdx.x & 63;
    if (wid >= NT) return;
    int cnt = cur_t[wid];
    float a0 = 0.f, a1 = 0.f, a2 = 0.f, a3 = 0.f;
    for (int j = lane; j < cnt; j += 64) {
        int s = adjs[wid * CAP_T + j];
        float4 v = *(const float4*)(xl + (size_t)s * LIG_IN);
        a0 += v.x; a1 += v.y; a2 += v.z; a3 += v.w;
    }
#pragma unroll
    for (int off = 32; off > 0; off >>= 1) {
        a0 += __shfl_xor(a0, off);
        a1 += __shfl_xor(a1, off);
        a2 += __shfl_xor(a2, off);
        a3 += __shfl_xor(a3, off);
    }
    float inv = 1.0f / fmaxf((float)cnt, 1.0f);
    a0 *= inv; a1 *= inv; a2 *= inv; a3 *= inv;
    float acc = 0.f;
#pragma unroll
    for (int p = 0; p < 2; ++p) {
        int h = lane + p * 64;
        float v = a0 * W_lt_l[h] + a1 * W_lt_l[H + h] + a2 * W_lt_l[2 * H + h] +
                  a3 * W_lt_l[3 * H + h] + b_lt_l[h] + t_lin[(size_t)wid * H + h];
        v = fmaxf(v, 0.f);
        acc += v * W_ep[H + h];
    }
#pragma unroll
    for (int off = 32; off > 0; off >>= 1) acc += __shfl_down(acc, off);
    if (lane == 0) st[wid] = acc;
}

// ---- fused ligand gather + post (wave per ligand) -------------------------
__global__ void ligand_gather_post(const int* __restrict__ cur_l, const int* __restrict__ adjd,
                                   const float* __restrict__ y_tl,
                                   const float* __restrict__ xl,
                                   const float* __restrict__ W_tl_r, const float* __restrict__ b_tl_l,
                                   const float* __restrict__ W_ep,
                                   float* __restrict__ sl, int NL)
{
    int wid = (blockIdx.x * blockDim.x + threadIdx.x) >> 6;
    int lane = threadIdx.x & 63;
    if (wid >= NL) return;
    int cnt = cur_l[wid];
    float a0 = 0.f, a1 = 0.f;   // h = 2*lane, 2*lane+1
    for (int j = 0; j < cnt; ++j) {
        int d = adjd[wid * CAP_L + j];
        float2 f = ((const float2*)(y_tl + (size_t)d * H))[lane];  // one 512B row load
        a0 += f.x;
        a1 += f.y;
    }
    float inv = 1.0f / fmaxf((float)cnt, 1.0f);
    float4 x = *(const float4*)(xl + (size_t)wid * LIG_IN);
    float acc = 0.f;
    {
        int h = 2 * lane;
        float v = a0 * inv + b_tl_l[h] +
                  x.x * W_tl_r[h] + x.y * W_tl_r[H + h] +
                  x.z * W_tl_r[2 * H + h] + x.w * W_tl_r[3 * H + h];
        v = fmaxf(v, 0.f);
        acc += v * W_ep[h];
    }
    {
        int h = 2 * lane + 1;
        float v = a1 * inv + b_tl_l[h] +
                  x.x * W_tl_r[h] + x.y * W_tl_r[H + h] +
                  x.z * W_tl_r[2 * H + h] + x.w * W_tl_r[3 * H + h];
        v = fmaxf(v, 0.f);
        acc += v * W_ep[h];
    }
#pragma unroll
    for (int off = 32; off > 0; off >>= 1) acc += __shfl_down(acc, off);
    if (lane == 0) sl[wid] = acc;
}

// ---- final edge output ----------------------------------------------------
__global__ void edge_out(const int* __restrict__ src, const int* __restrict__ dst,
                         const float* __restrict__ sl, const float* __restrict__ st,
                         const float* __restrict__ b_ep, float* __restrict__ out, int E)
{
    int e = blockIdx.x * blockDim.x + threadIdx.x;
    if (e >= E) return;
    out[e] = sl[src[e]] + st[dst[e]] + b_ep[0];
}

// ---------------------------------------------------------------------------
extern "C" void kernel_launch(void* const* d_in, const int* in_sizes, int n_in,
                              void* d_out, int out_size, void* d_ws, size_t ws_size,
                              hipStream_t stream) {
    const float* x_ligand = (const float*)d_in[0];
    const float* x_target = (const float*)d_in[1];
    const int*   edge_src = (const int*)d_in[2];
    const int*   edge_dst = (const int*)d_in[3];
    const float* W_lt_l   = (const float*)d_in[4];
    const float* b_lt_l   = (const float*)d_in[5];
    const float* W_lt_r   = (const float*)d_in[6];
    const float* W_tl_l   = (const float*)d_in[7];
    const float* b_tl_l   = (const float*)d_in[8];
    const float* W_tl_r   = (const float*)d_in[9];
    const float* W_ep     = (const float*)d_in[10];
    const float* b_ep     = (const float*)d_in[11];
    float* out = (float*)d_out;

    const int NL = in_sizes[0] / LIG_IN;   // 100000
    const int NT = in_sizes[1] / K_DIM;    // 20000
    const int E  = in_sizes[2];            // 250000

    // ---- workspace layout (16B-aligned offsets) ----
    char* ws = (char*)d_ws;
    size_t off = 0;
    auto take = [&](size_t bytes) { size_t o = off; off += (bytes + 15) & ~(size_t)15; return o; };
    size_t off_Wt     = take((size_t)2 * H * K_DIM * 2); // 655 KB bf16
    size_t off_y_tl   = take((size_t)NT * H * 4);        // 10.24 MB
    size_t off_t_lin  = take((size_t)NT * H * 4);        // 10.24 MB
    size_t off_adjd   = take((size_t)NL * CAP_L * 4);    // 9.6 MB
    size_t off_adjs   = take((size_t)NT * CAP_T * 4);    // 3.84 MB
    size_t off_cur_l  = take((size_t)NL * 4);            // <- memset start
    size_t off_cur_t  = take((size_t)NT * 4);            // <- memset end
    size_t off_sl     = take((size_t)NL * 4);
    size_t off_st     = take((size_t)NT * 4);
    if (off > ws_size) {
        hipMemsetAsync(d_out, 0, (size_t)out_size * 4, stream);
        return;
    }

    __hip_bfloat16* Wt = (__hip_bfloat16*)(ws + off_Wt);
    float* y_tl  = (float*)(ws + off_y_tl);
    float* t_lin = (float*)(ws + off_t_lin);
    int*   adjd  = (int*)(ws + off_adjd);
    int*   adjs  = (int*)(ws + off_adjs);
    int*   cur_l = (int*)(ws + off_cur_l);
    int*   cur_t = (int*)(ws + off_cur_t);
    float* sl    = (float*)(ws + off_sl);
    float* st    = (float*)(ws + off_st);

    // zero the cursors (contiguous)
    hipMemsetAsync(cur_l, 0, off_sl - off_cur_l, stream);

    // 1. weight cast (GEMM needs it first)
    int nw = 2 * H * K_DIM;
    cast_wt<<<(nw + 255) / 256, 256, 0, stream>>>(W_tl_l, W_lt_r, Wt, nw);

    // 2. GEMM: grid 626 (mb = bid>>1, nb = bid&1)
    gemm_fused<<<((NT + 63) / 64) * 2, 256, 0, stream>>>(x_target, (const unsigned short*)Wt,
                                                         y_tl, t_lin, NT);

    // 3. adjacency build (1 atomic per edge per side)
    fill_both<<<(E + 255) / 256, 256, 0, stream>>>(edge_src, edge_dst,
                                                   cur_l, cur_t, adjd, adjs, E);

    // 4. target post -> st (gathers x_ligand via adjs)
    target_post<<<(NT * 64 + 255) / 256, 256, 0, stream>>>(cur_t, adjs, x_ligand, t_lin,
                                                           W_lt_l, b_lt_l, W_ep, st, NT);
    // 5. ligand gather + post -> sl
    ligand_gather_post<<<(NL * 64 + 255) / 256, 256, 0, stream>>>(cur_l, adjd, y_tl, x_ligand,
                                                                  W_tl_r, b_tl_l, W_ep, sl, NL);
    // 6. edge output
    edge_out<<<(E + 255) / 256, 256, 0, stream>>>(edge_src, edge_dst, sl, st, b_ep, out, E);
}